// Round 2
// baseline (340.544 us; speedup 1.0000x reference)
//
#include <hip/hip_runtime.h>

// Problem constants (match reference)
constexpr int NB   = 16;    // batch
constexpr int CIN  = 256;
constexpr int COUT = 256;
constexpr int TDIM = 4096;
constexpr int KS   = 3;
constexpr int PADV = 1;

// Tiling
constexpr int TT = 128;   // t per block
constexpr int TO = 128;   // output channels per block
constexpr int CC = 16;    // c per LDS chunk

// d_ws usage: wT[k][c][o] transposed weight, 3*256*256*4 = 768 KB
__global__ __launch_bounds__(256) void transpose_w(const float* __restrict__ w,
                                                   float* __restrict__ wT) {
    int idx = blockIdx.x * 256 + threadIdx.x;   // COUT*CIN*KS = 196608
    if (idx >= COUT * CIN * KS) return;
    int k = idx % KS;
    int c = (idx / KS) % CIN;
    int o = idx / (KS * CIN);
    wT[(k * CIN + c) * COUT + o] = w[idx];
}

__global__ __launch_bounds__(256) void deform_gemm(
    const float* __restrict__ x,     // (NB, CIN, TDIM)
    const float* __restrict__ off,   // (NB, 2*KS, TDIM, 1)
    const float* __restrict__ wT,    // (KS, CIN, COUT)
    const float* __restrict__ bias,  // (COUT)
    float* __restrict__ out)         // (NB, COUT, TDIM)
{
    __shared__ __align__(16) float vs[CC][TT];
    __shared__ __align__(16) float ws[CC][TO];
    __shared__ int   sI0[KS][TT];
    __shared__ int   sI1[KS][TT];
    __shared__ float sW0[KS][TT];
    __shared__ float sW1[KS][TT];

    const int tid = threadIdx.x;
    const int tt0 = blockIdx.x * TT;
    const int oo0 = blockIdx.y * TO;
    const int b   = blockIdx.z;

    // ---- Phase A: per-(k,t) indices & interp weights ----
    for (int item = tid; item < KS * TT; item += 256) {
        int k = item >> 7;           // TT = 128
        int j = item & (TT - 1);
        int t = tt0 + j;
        float dyr = off[((b * 2 * KS + 2 * k) * TDIM) + t];
        float dxr = off[((b * 2 * KS + 2 * k + 1) * TDIM) + t];
        float dy  = dyr - (float)(k - PADV);           // dy - base_y
        float py  = (float)(t - PADV + k) + dy;        // t0 + k + dy
        float i0f = floorf(py);
        float frac = py - i0f;
        int i0 = (int)i0f;
        int i1 = i0 + 1;
        float wx = fmaxf(0.0f, 1.0f - fabsf(dxr));
        float w0 = (1.0f - frac) * wx * ((i0 >= 0 && i0 < TDIM) ? 1.0f : 0.0f);
        float w1 = frac * wx * ((i1 >= 0 && i1 < TDIM) ? 1.0f : 0.0f);
        sI0[k][j] = min(max(i0, 0), TDIM - 1);
        sI1[k][j] = min(max(i1, 0), TDIM - 1);
        sW0[k][j] = w0;
        sW1[k][j] = w1;
    }

    float acc[8][8];   // [o-dim][t-dim]
    #pragma unroll
    for (int i = 0; i < 8; ++i)
        #pragma unroll
        for (int j = 0; j < 8; ++j) acc[i][j] = 0.0f;

    const int tr = tid >> 4;   // 0..15  -> o dimension
    const int tc = tid & 15;   // 0..15  -> t dimension

    for (int k = 0; k < KS; ++k) {
      for (int c0 = 0; c0 < CIN; c0 += CC) {
        __syncthreads();   // protect LDS (also covers Phase A -> first reads)

        // stage v: CC x TT = 2048 elems, 8 per thread, lanes stride-1 in t
        #pragma unroll
        for (int it = 0; it < (CC * TT) / 256; ++it) {
            int flat = it * 256 + tid;
            int c = flat >> 7;          // / TT
            int j = flat & (TT - 1);
            const float* xr = x + (size_t)(b * CIN + c0 + c) * TDIM;
            vs[c][j] = xr[sI0[k][j]] * sW0[k][j] + xr[sI1[k][j]] * sW1[k][j];
        }
        // stage w: CC x TO elems, coalesced from wT
        #pragma unroll
        for (int it = 0; it < (CC * TO) / 256; ++it) {
            int flat = it * 256 + tid;
            int c = flat >> 7;          // / TO
            int o = flat & (TO - 1);
            ws[c][o] = wT[((k * CIN) + (c0 + c)) * COUT + oo0 + o];
        }
        __syncthreads();

        #pragma unroll
        for (int c = 0; c < CC; ++c) {
            float4 wv0 = *(const float4*)&ws[c][tr * 4];
            float4 wv1 = *(const float4*)&ws[c][tr * 4 + 64];
            float4 vv0 = *(const float4*)&vs[c][tc * 4];
            float4 vv1 = *(const float4*)&vs[c][tc * 4 + 64];
            float wr[8] = {wv0.x, wv0.y, wv0.z, wv0.w, wv1.x, wv1.y, wv1.z, wv1.w};
            float vr[8] = {vv0.x, vv0.y, vv0.z, vv0.w, vv1.x, vv1.y, vv1.z, vv1.w};
            #pragma unroll
            for (int i = 0; i < 8; ++i)
                #pragma unroll
                for (int j = 0; j < 8; ++j)
                    acc[i][j] = fmaf(wr[i], vr[j], acc[i][j]);
        }
      }
    }

    // ---- Epilogue: coalesced float4 stores (lanes vary in t) ----
    #pragma unroll
    for (int io = 0; io < 8; ++io) {
        int o = oo0 + tr * 4 + (io & 3) + ((io >> 2) << 6);
        float bv = bias[o];
        float* orow = out + (size_t)(b * COUT + o) * TDIM + tt0;
        float4 s0 = make_float4(acc[io][0] + bv, acc[io][1] + bv,
                                acc[io][2] + bv, acc[io][3] + bv);
        float4 s1 = make_float4(acc[io][4] + bv, acc[io][5] + bv,
                                acc[io][6] + bv, acc[io][7] + bv);
        *(float4*)&orow[tc * 4]      = s0;
        *(float4*)&orow[tc * 4 + 64] = s1;
    }
}

extern "C" void kernel_launch(void* const* d_in, const int* in_sizes, int n_in,
                              void* d_out, int out_size, void* d_ws, size_t ws_size,
                              hipStream_t stream) {
    const float* x    = (const float*)d_in[0];
    const float* off  = (const float*)d_in[1];
    const float* w    = (const float*)d_in[2];
    const float* bias = (const float*)d_in[3];
    float* out = (float*)d_out;
    float* wT  = (float*)d_ws;    // needs 768 KB

    transpose_w<<<dim3((COUT * CIN * KS + 255) / 256), dim3(256), 0, stream>>>(w, wT);

    dim3 grid(TDIM / TT, COUT / TO, NB);
    deform_gemm<<<grid, dim3(256), 0, stream>>>(x, off, wT, bias, out);
}

// Round 3
// 113.884 us; speedup vs baseline: 2.9903x; 2.9903x over previous
//
#include <hip/hip_runtime.h>
#include <hip/hip_bf16.h>

typedef __attribute__((ext_vector_type(8))) short bf16x8;
typedef __attribute__((ext_vector_type(4))) float f32x4;

constexpr int NB = 16, CIN = 256, COUT = 256, TDIM = 4096, KS = 3, PADV = 1;
constexpr int TT = 128;            // t per block
constexpr int BK = 64;             // K-step (kc = k*CIN + c)
constexpr int KTOT = KS * CIN;     // 768
constexpr int NSTEP = KTOT / BK;   // 12

static __device__ __forceinline__ ushort f2bf(float f) {
    union { __hip_bfloat16 h; ushort u; } cv;
    cv.h = __float2bfloat16(f);
    return cv.u;
}

// wPack[o][k*CIN + c] = bf16(w[o][c][k]); 256*768*2B = 384 KB in d_ws
__global__ __launch_bounds__(256) void prepack_w(const float* __restrict__ w,
                                                 __hip_bfloat16* __restrict__ wp) {
    int idx = blockIdx.x * 256 + threadIdx.x;      // COUT*KTOT = 196608
    if (idx >= COUT * KTOT) return;
    int o = idx / KTOT;
    int r = idx - o * KTOT;
    int k = r >> 8;                                // / CIN
    int c = r & (CIN - 1);
    wp[idx] = __float2bfloat16(w[(o * CIN + c) * KS + k]);
}

__global__ __launch_bounds__(512) void deform_mfma(
    const float* __restrict__ x,              // (NB, CIN, TDIM)
    const float* __restrict__ off,            // (NB, 2*KS, TDIM, 1)
    const __hip_bfloat16* __restrict__ wp,    // (COUT, KTOT)
    const float* __restrict__ bias,           // (COUT)
    float* __restrict__ out)                  // (NB, COUT, TDIM)
{
    // XOR-swizzled LDS tiles: byte ^= ((row&7)<<4). Rows are 128 B (64 bf16).
    __shared__ ushort w_s[COUT * BK];   // [o][kk]  32 KB
    __shared__ ushort v_s[TT * BK];     // [t][kk]  16 KB
    __shared__ int4   sP[KS][TT];       // {i0, i1, w0f, w1f} per (k, t)  6 KB

    const int tid = threadIdx.x;
    const int b   = blockIdx.y;
    const int tt0 = blockIdx.x * TT;

    // ---- Phase A: per-(k,t) gather indices & interp weights ----
    if (tid < KS * TT) {
        int k = tid >> 7, j = tid & (TT - 1);
        int t = tt0 + j;
        float dyr = off[((b * 2 * KS + 2 * k) * TDIM) + t];
        float dxr = off[((b * 2 * KS + 2 * k + 1) * TDIM) + t];
        // py = t0 + k + (dyr - (k-PAD)) with t0 = t - PAD
        float py  = (float)(t - PADV + k) + dyr - (float)(k - PADV);
        float i0f = floorf(py);
        float fr  = py - i0f;
        int i0 = (int)i0f, i1 = i0 + 1;
        float wx = fmaxf(0.0f, 1.0f - fabsf(dxr));
        float w0 = (1.0f - fr) * wx * ((i0 >= 0 && i0 < TDIM) ? 1.0f : 0.0f);
        float w1 = fr * wx * ((i1 >= 0 && i1 < TDIM) ? 1.0f : 0.0f);
        int4 p;
        p.x = min(max(i0, 0), TDIM - 1);
        p.y = min(max(i1, 0), TDIM - 1);
        p.z = __float_as_int(w0);
        p.w = __float_as_int(w1);
        sP[k][j] = p;
    }

    const int wid    = tid >> 6;
    const int lane   = tid & 63;
    const int o_base = (wid >> 1) * 64;   // 4 wave-rows in o
    const int t_base = (wid & 1) * 64;    // 2 wave-cols in t
    const int lr     = lane & 15;         // fragment row/col
    const int lg     = lane >> 4;         // k-group (8 bf16 each)

    f32x4 acc[4][4];
    #pragma unroll
    for (int i = 0; i < 4; ++i)
        #pragma unroll
        for (int j = 0; j < 4; ++j) acc[i][j] = (f32x4)0.0f;

    const float* xb = x + (size_t)b * CIN * TDIM;

    for (int ks = 0; ks < NSTEP; ++ks) {
        const int kc0 = ks * BK;
        const int k   = kc0 >> 8;          // kernel tap for this chunk
        const int c0  = kc0 & (CIN - 1);   // channel base
        __syncthreads();                   // prev compute done; sP visible (ks=0)

        // ---- stage W: 256x64 bf16, coalesced b128 from wPack ----
        #pragma unroll
        for (int it = 0; it < 4; ++it) {
            int oid = it * 512 + tid;          // octet id 0..2047
            int o = oid >> 3, oc = oid & 7;
            bf16x8 g = *(const bf16x8*)(wp + (size_t)o * KTOT + kc0 + oc * 8);
            int byte = (o * (BK * 2) + oc * 16) ^ ((o & 7) << 4);
            *(bf16x8*)((char*)w_s + byte) = g;
        }

        // ---- stage V: 128x64 bf16 via gather+interp+cast ----
        #pragma unroll
        for (int it = 0; it < 2; ++it) {
            int oid = it * 512 + tid;          // octet id 0..1023
            int coct = oid >> 7;               // which 8-channel group
            int t = oid & (TT - 1);            // lanes consecutive in t -> coalesced gathers
            int4 p = sP[k][t];
            float w0 = __int_as_float(p.z), w1 = __int_as_float(p.w);
            const float* xr = xb + (size_t)(c0 + coct * 8) * TDIM;
            bf16x8 pk;
            #pragma unroll
            for (int i = 0; i < 8; ++i) {
                float v = xr[p.x] * w0 + xr[p.y] * w1;
                pk[i] = (short)f2bf(v);
                xr += TDIM;
            }
            int byte = (t * (BK * 2) + coct * 16) ^ ((t & 7) << 4);
            *(bf16x8*)((char*)v_s + byte) = pk;
        }

        __syncthreads();

        // ---- MFMA: wave computes 64(o) x 64(t), K=64 ----
        #pragma unroll
        for (int kb = 0; kb < 2; ++kb) {
            bf16x8 af[4], bfr[4];
            #pragma unroll
            for (int mf = 0; mf < 4; ++mf) {
                int o  = o_base + mf * 16 + lr;
                int kk = kb * 32 + lg * 8;
                int byte = (o * (BK * 2) + kk * 2) ^ ((o & 7) << 4);
                af[mf] = *(const bf16x8*)((const char*)w_s + byte);
            }
            #pragma unroll
            for (int nf = 0; nf < 4; ++nf) {
                int t  = t_base + nf * 16 + lr;
                int kk = kb * 32 + lg * 8;
                int byte = (t * (BK * 2) + kk * 2) ^ ((t & 7) << 4);
                bfr[nf] = *(const bf16x8*)((const char*)v_s + byte);
            }
            #pragma unroll
            for (int mf = 0; mf < 4; ++mf)
                #pragma unroll
                for (int nf = 0; nf < 4; ++nf)
                    acc[mf][nf] = __builtin_amdgcn_mfma_f32_16x16x32_bf16(
                        af[mf], bfr[nf], acc[mf][nf], 0, 0, 0);
        }
    }

    // ---- Epilogue: D col = lane&15 (t), row = (lane>>4)*4 + reg (o) ----
    #pragma unroll
    for (int mf = 0; mf < 4; ++mf) {
        #pragma unroll
        for (int r = 0; r < 4; ++r) {
            int o = o_base + mf * 16 + lg * 4 + r;
            float bv = bias[o];
            float* orow = out + (size_t)(b * COUT + o) * TDIM + tt0 + t_base;
            #pragma unroll
            for (int nf = 0; nf < 4; ++nf)
                orow[nf * 16 + lr] = acc[mf][nf][r] + bv;
        }
    }
}

extern "C" void kernel_launch(void* const* d_in, const int* in_sizes, int n_in,
                              void* d_out, int out_size, void* d_ws, size_t ws_size,
                              hipStream_t stream) {
    const float* x    = (const float*)d_in[0];
    const float* off  = (const float*)d_in[1];
    const float* w    = (const float*)d_in[2];
    const float* bias = (const float*)d_in[3];
    float* out = (float*)d_out;
    __hip_bfloat16* wp = (__hip_bfloat16*)d_ws;   // 384 KB

    prepack_w<<<dim3((COUT * KTOT + 255) / 256), dim3(256), 0, stream>>>(w, wp);

    dim3 grid(TDIM / TT, NB);
    deform_mfma<<<grid, dim3(512), 0, stream>>>(x, off, wp, bias, out);
}

// Round 4
// 81.117 us; speedup vs baseline: 4.1982x; 1.4039x over previous
//
#include <hip/hip_runtime.h>
#include <hip/hip_bf16.h>

typedef __attribute__((ext_vector_type(8))) short bf16x8;
typedef __attribute__((ext_vector_type(4))) float f32x4;

constexpr int NB = 16, CIN = 256, COUT = 256, TDIM = 4096, KS = 3, PADV = 1;
constexpr int TT = 128;            // t per block
constexpr int BK = 64;             // K-step (kc = k*CIN + c)
constexpr int KTOT = KS * CIN;     // 768
constexpr int NSTEP = KTOT / BK;   // 12

typedef __attribute__((address_space(1))) const unsigned int gu32;
typedef __attribute__((address_space(3))) unsigned int lu32;

static __device__ __forceinline__ ushort f2bf(float f) {
    union { __hip_bfloat16 h; ushort u; } cv;
    cv.h = __float2bfloat16(f);
    return cv.u;
}

// wp[ks][o][j][e] = bf16(W[o][kc]) with kc = ks*BK + (j ^ (o&7))*8 + e.
// This is the per-step LDS image PRE-swizzled so that a linear
// global_load_lds lands in LDS such that byte (o*128 + oc*16)^((o&7)<<4)
// holds W[o][kc0 + oc*8 .. +8]  (same read swizzle as the MFMA phase).
__global__ __launch_bounds__(256) void prepack_w(const float* __restrict__ w,
                                                 __hip_bfloat16* __restrict__ wp) {
    int idx = blockIdx.x * 256 + threadIdx.x;      // NSTEP*COUT*BK = 196608
    if (idx >= NSTEP * COUT * BK) return;
    int e  = idx & 7;
    int j  = (idx >> 3) & 7;
    int o  = (idx >> 6) & (COUT - 1);
    int ks = idx >> 14;
    int kc = ks * BK + ((j ^ (o & 7)) << 3) + e;
    int k  = kc >> 8;              // / CIN
    int c  = kc & (CIN - 1);
    wp[idx] = __float2bfloat16(w[(o * CIN + c) * KS + k]);
}

__global__ __launch_bounds__(512, 4) void deform_mfma(
    const float* __restrict__ x,              // (NB, CIN, TDIM)
    const float* __restrict__ off,            // (NB, 2*KS, TDIM, 1)
    const __hip_bfloat16* __restrict__ wp,    // swizzled pack, 384 KB
    const float* __restrict__ bias,           // (COUT)
    float* __restrict__ out)                  // (NB, COUT, TDIM)
{
    __shared__ ushort w_s[COUT * BK];   // 32 KB, swizzled image per step
    __shared__ ushort v_s[TT * BK];     // 16 KB, swizzled
    __shared__ int4   sP[KS][TT];       // {i0, i1, w0f, w1f} per (k, t)  6 KB

    const int tid = threadIdx.x;
    const int b   = blockIdx.y;
    const int tt0 = blockIdx.x * TT;

    // ---- Phase A: per-(k,t) gather indices & interp weights ----
    if (tid < KS * TT) {
        int k = tid >> 7, j = tid & (TT - 1);
        int t = tt0 + j;
        float dyr = off[((b * 2 * KS + 2 * k) * TDIM) + t];
        float dxr = off[((b * 2 * KS + 2 * k + 1) * TDIM) + t];
        float py  = (float)(t - PADV + k) + dyr - (float)(k - PADV);
        float i0f = floorf(py);
        float fr  = py - i0f;
        int i0 = (int)i0f, i1 = i0 + 1;
        float wx = fmaxf(0.0f, 1.0f - fabsf(dxr));
        float w0 = (1.0f - fr) * wx * ((i0 >= 0 && i0 < TDIM) ? 1.0f : 0.0f);
        float w1 = fr * wx * ((i1 >= 0 && i1 < TDIM) ? 1.0f : 0.0f);
        int4 p;
        p.x = min(max(i0, 0), TDIM - 1);
        p.y = min(max(i1, 0), TDIM - 1);
        p.z = __float_as_int(w0);
        p.w = __float_as_int(w1);
        sP[k][j] = p;
    }

    const int wid    = tid >> 6;
    const int lane   = tid & 63;
    const int o_base = (wid >> 1) * 64;   // 4 wave-rows in o
    const int t_base = (wid & 1) * 64;    // 2 wave-cols in t
    const int lr     = lane & 15;
    const int lg     = lane >> 4;

    f32x4 acc[4][4];
    #pragma unroll
    for (int i = 0; i < 4; ++i)
        #pragma unroll
        for (int j = 0; j < 4; ++j) acc[i][j] = (f32x4)0.0f;

    const float* xb = x + (size_t)b * CIN * TDIM;

    for (int ks = 0; ks < NSTEP; ++ks) {
        const int kc0 = ks * BK;
        const int k   = kc0 >> 8;
        const int c0  = kc0 & (CIN - 1);
        __syncthreads();   // MFMA(ks-1) done -> LDS writable; sP visible (ks=0)

        // ---- stage W: direct global->LDS DMA, pre-swizzled source ----
        {
            const char* gbase = (const char*)wp + (size_t)ks * 32768 + wid * 4096 + lane * 16;
            char* lbase = (char*)w_s + wid * 4096;   // wave-uniform
            #pragma unroll
            for (int i = 0; i < 4; ++i)
                __builtin_amdgcn_global_load_lds((gu32*)(gbase + i * 1024),
                                                 (lu32*)(lbase + i * 1024), 16, 0, 0);
        }

        // ---- stage V: ALL 32 gather loads first, then math ----
        {
            const int coct0 = tid >> 7;          // 0..3
            const int t     = tid & (TT - 1);
            int4 p = sP[k][t];
            const float* xr0 = xb + (size_t)(c0 + coct0 * 8) * TDIM;
            const float* xr1 = xr0 + (size_t)32 * TDIM;   // coct0+4
            float g0[16], g1[16];
            #pragma unroll
            for (int i = 0; i < 8; ++i) {
                g0[2 * i]     = xr0[p.x];
                g0[2 * i + 1] = xr0[p.y];
                xr0 += TDIM;
            }
            #pragma unroll
            for (int i = 0; i < 8; ++i) {
                g1[2 * i]     = xr1[p.x];
                g1[2 * i + 1] = xr1[p.y];
                xr1 += TDIM;
            }
            float w0 = __int_as_float(p.z), w1 = __int_as_float(p.w);
            bf16x8 pk0, pk1;
            #pragma unroll
            for (int i = 0; i < 8; ++i) {
                pk0[i] = (short)f2bf(g0[2 * i] * w0 + g0[2 * i + 1] * w1);
                pk1[i] = (short)f2bf(g1[2 * i] * w0 + g1[2 * i + 1] * w1);
            }
            int row = t * (BK * 2);
            int swz = (t & 7) << 4;
            *(bf16x8*)((char*)v_s + ((row + coct0 * 16) ^ swz))       = pk0;
            *(bf16x8*)((char*)v_s + ((row + (coct0 + 4) * 16) ^ swz)) = pk1;
        }

        __syncthreads();   // drains gathers + load_lds + ds_writes

        // ---- MFMA: wave computes 64(o) x 64(t), K=64 ----
        #pragma unroll
        for (int kb = 0; kb < 2; ++kb) {
            bf16x8 af[4], bfr[4];
            #pragma unroll
            for (int mf = 0; mf < 4; ++mf) {
                int o  = o_base + mf * 16 + lr;
                int kk = kb * 32 + lg * 8;
                int byte = (o * (BK * 2) + kk * 2) ^ ((o & 7) << 4);
                af[mf] = *(const bf16x8*)((const char*)w_s + byte);
            }
            #pragma unroll
            for (int nf = 0; nf < 4; ++nf) {
                int t  = t_base + nf * 16 + lr;
                int kk = kb * 32 + lg * 8;
                int byte = (t * (BK * 2) + kk * 2) ^ ((t & 7) << 4);
                bfr[nf] = *(const bf16x8*)((const char*)v_s + byte);
            }
            #pragma unroll
            for (int mf = 0; mf < 4; ++mf)
                #pragma unroll
                for (int nf = 0; nf < 4; ++nf)
                    acc[mf][nf] = __builtin_amdgcn_mfma_f32_16x16x32_bf16(
                        af[mf], bfr[nf], acc[mf][nf], 0, 0, 0);
        }
    }

    // ---- Epilogue: D col = lane&15 (t), row = (lane>>4)*4 + reg (o) ----
    #pragma unroll
    for (int mf = 0; mf < 4; ++mf) {
        #pragma unroll
        for (int r = 0; r < 4; ++r) {
            int o = o_base + mf * 16 + lg * 4 + r;
            float bv = bias[o];
            float* orow = out + (size_t)(b * COUT + o) * TDIM + tt0 + t_base;
            #pragma unroll
            for (int nf = 0; nf < 4; ++nf)
                orow[nf * 16 + lr] = acc[mf][nf][r] + bv;
        }
    }
}

extern "C" void kernel_launch(void* const* d_in, const int* in_sizes, int n_in,
                              void* d_out, int out_size, void* d_ws, size_t ws_size,
                              hipStream_t stream) {
    const float* x    = (const float*)d_in[0];
    const float* off  = (const float*)d_in[1];
    const float* w    = (const float*)d_in[2];
    const float* bias = (const float*)d_in[3];
    float* out = (float*)d_out;
    __hip_bfloat16* wp = (__hip_bfloat16*)d_ws;   // 384 KB swizzled pack

    prepack_w<<<dim3((NSTEP * COUT * BK + 255) / 256), dim3(256), 0, stream>>>(w, wp);

    dim3 grid(TDIM / TT, NB);
    deform_mfma<<<grid, dim3(512), 0, stream>>>(x, off, wp, bias, out);
}